// Round 37
// baseline (89.943 us; speedup 1.0000x reference)
//
#include <hip/hip_runtime.h>
#include <cmath>
#include <stdint.h>

#pragma clang fp contract(off)

// Register barrier: isolates each FP op (no contraction/reassociation).
__device__ __forceinline__ void opqf(float& v) { asm volatile("" : "+v"(v)); }

__device__ __forceinline__ uint32_t fbits(float f) { return __float_as_uint(f); }
__device__ __forceinline__ float bitsf(uint32_t u) { return __uint_as_float(u); }

// combos = sorted(itertools.combinations(range(8), 2))
__device__ __constant__ int d_CI[28] = {0,0,0,0,0,0,0,1,1,1,1,1,1,2,2,2,2,2,3,3,3,3,4,4,4,5,5,6};
__device__ __constant__ int d_CJ[28] = {1,2,3,4,5,6,7,2,3,4,5,6,7,3,4,5,6,7,4,5,6,7,5,6,7,6,7,7};

// Pair table in a-outer form: for each a, the list of disjoint b's (byte
// offsets). Generated at compile time mirroring the reference PAIRS order.
struct PairTabs {
    uint16_t boff[210];   // b*4 byte offsets, grouped by a, PAIRS order
    uint16_t start[29];   // start[a]..start[a+1] = b-range for this a
};
constexpr PairTabs make_pairs() {
    PairTabs t{};
    int CI_[28] = {0,0,0,0,0,0,0,1,1,1,1,1,1,2,2,2,2,2,3,3,3,3,4,4,4,5,5,6};
    int CJ_[28] = {1,2,3,4,5,6,7,2,3,4,5,6,7,3,4,5,6,7,4,5,6,7,5,6,7,6,7,7};
    int k = 0;
    for (int a = 0; a < 28; ++a) {
        t.start[a] = (uint16_t)k;
        for (int b = a + 1; b < 28; ++b) {
            unsigned ma = (1u << CI_[a]) | (1u << CJ_[a]);
            unsigned mb = (1u << CI_[b]) | (1u << CJ_[b]);
            if (ma & mb) continue;
            t.boff[k++] = (uint16_t)(b * 4);
        }
    }
    t.start[28] = (uint16_t)k;   // == 210
    return t;
}
__device__ __constant__ PairTabs d_PT = make_pairs();

__global__ __launch_bounds__(128) void mass_asym_kernel(const float* __restrict__ x,
                                                        float* __restrict__ out,
                                                        int n) {
#pragma clang fp contract(off)
    __shared__ float sm[128 * 29];                      // stride 29: 2-lane/bank (free)
    int t = blockIdx.x * blockDim.x + threadIdx.x;
    if (t >= n) return;

    constexpr int CI[28] = {0,0,0,0,0,0,0,1,1,1,1,1,1,2,2,2,2,2,3,3,3,3,4,4,4,5,5,6};
    constexpr int CJ[28] = {1,2,3,4,5,6,7,2,3,4,5,6,7,3,4,5,6,7,4,5,6,7,5,6,7,6,7,7};

    const float4* xp = reinterpret_cast<const float4*>(x) + (size_t)t * 8;
    float E[8], px[8], py[8], pz[8];
#pragma unroll
    for (int i = 0; i < 8; ++i) {
        float4 v = xp[i];
        E[i] = v.x; px[i] = v.y; py[i] = v.z; pz[i] = v.w;
    }

    float* myrow = &sm[threadIdx.x * 29];

    // PROVEN REFERENCE PIPELINE (R32-R36, passes absmax 4.5):
    //   acc0 = a*a; acc1 = b*b; acc0 = fma(d,d,acc0); s = acc0+acc1
    //   e2 = e*e; m2 = e2 - s;  m = HW CR f32 sqrt
#pragma unroll
    for (int c = 0; c < 28; ++c) {
        float e = E[CI[c]]  + E[CJ[c]];  opqf(e);
        float a = px[CI[c]] + px[CJ[c]]; opqf(a);
        float b = py[CI[c]] + py[CJ[c]]; opqf(b);
        float d = pz[CI[c]] + pz[CJ[c]]; opqf(d);
        float acc0 = a * a; opqf(acc0);
        float acc1 = b * b; opqf(acc1);
        acc0 = __builtin_fmaf(d, d, acc0); opqf(acc0);
        float s = acc0 + acc1; opqf(s);
        float e2 = e * e; opqf(e2);
        float m2 = e2 - s; opqf(m2);
        myrow[c] = sqrtf(m2);                       // HW CR f32 sqrt
    }

    // Pair scan, a-outer / b-inner (same PAIRS lexicographic order ->
    // identical first-min semantics). m[a] loaded ONCE per outer iter:
    // 28 + 210 LDS reads instead of 420. Same IEEE op sequence per pair
    // (sub, |.|, add, CR divide, uint strict-<) -> bit-identical selection.
    const char* rowbytes = (const char*)myrow;
    uint32_t ubest = 0x7f800000u;   // +inf
    uint32_t bpent = 0;             // (a<<16) | b_byte_offset of winner
#pragma unroll 1
    for (int a = 0; a < 27; ++a) {
        float va = myrow[a];
        const int s0 = d_PT.start[a], s1 = d_PT.start[a + 1];
#pragma unroll 4
        for (int p = s0; p < s1; ++p) {
            uint32_t bo = d_PT.boff[p];             // uniform -> SGPR
            float vb = *(const float*)(rowbytes + bo);
            float num = fabsf(va - vb);             // exact IEEE sub+abs
            float den = va + vb;                    // exact IEEE add
            float v = num / den;                    // HW CR f32 divide
            uint32_t uv = fbits(v);
            bool better = uv < ubest;
            ubest = better ? uv : ubest;
            bpent = better ? (((uint32_t)a << 16) | bo) : bpent;
        }
    }

    const int ba = (int)(bpent >> 16);
    const int bb = (int)((bpent & 0xffffu) >> 2);

    float bma = myrow[ba];
    float bmb = myrow[bb];

    float* o = out + (size_t)t * 7;
    o[0] = (float)d_CI[ba];
    o[1] = (float)d_CJ[ba];
    o[2] = (float)d_CI[bb];
    o[3] = (float)d_CJ[bb];
    o[4] = bma;
    o[5] = bmb;
    o[6] = bitsf(ubest);
}

extern "C" void kernel_launch(void* const* d_in, const int* in_sizes, int n_in,
                              void* d_out, int out_size, void* d_ws, size_t ws_size,
                              hipStream_t stream) {
    const float* x = (const float*)d_in[0];
    float* out = (float*)d_out;
    const int n = in_sizes[0] / 32;          // events
    const int block = 128;
    const int grid = (n + block - 1) / block;
    mass_asym_kernel<<<grid, block, 0, stream>>>(x, out, n);
}

// Round 38
// 65.790 us; speedup vs baseline: 1.3671x; 1.3671x over previous
//
#include <hip/hip_runtime.h>
#include <cmath>
#include <stdint.h>

#pragma clang fp contract(off)

// Register barrier: isolates each FP op (no contraction/reassociation).
// Used ONLY in the m^2 block (the contraction-sensitive part).
__device__ __forceinline__ void opqf(float& v) { asm volatile("" : "+v"(v)); }

__device__ __forceinline__ uint32_t fbits(float f) { return __float_as_uint(f); }
__device__ __forceinline__ float bitsf(uint32_t u) { return __uint_as_float(u); }

// combos = sorted(itertools.combinations(range(8), 2))
__device__ __constant__ int d_CI[28] = {0,0,0,0,0,0,0,1,1,1,1,1,1,2,2,2,2,2,3,3,3,3,4,4,4,5,5,6};
__device__ __constant__ int d_CJ[28] = {1,2,3,4,5,6,7,2,3,4,5,6,7,3,4,5,6,7,4,5,6,7,5,6,7,6,7,7};

__global__ __launch_bounds__(256) void mass_asym_kernel(const float* __restrict__ x,
                                                        float* __restrict__ out,
                                                        int n) {
#pragma clang fp contract(off)
    int t = blockIdx.x * blockDim.x + threadIdx.x;
    if (t >= n) return;

    constexpr int CI[28] = {0,0,0,0,0,0,0,1,1,1,1,1,1,2,2,2,2,2,3,3,3,3,4,4,4,5,5,6};
    constexpr int CJ[28] = {1,2,3,4,5,6,7,2,3,4,5,6,7,3,4,5,6,7,4,5,6,7,5,6,7,6,7,7};

    const float4* xp = reinterpret_cast<const float4*>(x) + (size_t)t * 8;
    float E[8], px[8], py[8], pz[8];
#pragma unroll
    for (int i = 0; i < 8; ++i) {
        float4 v = xp[i];
        E[i] = v.x; px[i] = v.y; py[i] = v.z; pz[i] = v.w;
    }

    // PROVEN REFERENCE PIPELINE (R32-R36, passes absmax 4.5):
    //   acc0 = a*a; acc1 = b*b; acc0 = fma(d,d,acc0); s = acc0+acc1
    //   e2 = e*e; m2 = e2 - s;  m = HW CR f32 sqrt
    // Masses stay in REGISTERS (static indices after full unroll).
    float m[28];
#pragma unroll
    for (int c = 0; c < 28; ++c) {
        float e = E[CI[c]]  + E[CJ[c]];  opqf(e);
        float a = px[CI[c]] + px[CJ[c]]; opqf(a);
        float b = py[CI[c]] + py[CJ[c]]; opqf(b);
        float d = pz[CI[c]] + pz[CJ[c]]; opqf(d);
        float acc0 = a * a; opqf(acc0);             // bare px^2
        float acc1 = b * b; opqf(acc1);             // bare py^2
        acc0 = __builtin_fmaf(d, d, acc0); opqf(acc0); // + pz^2 (fused)
        float s = acc0 + acc1; opqf(s);             // plain combining add
        float e2 = e * e; opqf(e2);                 // e^2 (rounds)
        float m2 = e2 - s; opqf(m2);                // plain subtract (rounds)
        m[c] = sqrtf(m2);                           // HW CR f32 sqrt
    }

    // 210 disjoint pairs, FULLY UNROLLED, lexicographic PAIRS order.
    // Exact IEEE op sequence (sub, abs, add, CR divide, uint strict-< =
    // first-min) -> selection bit-identical to the reference pipeline.
    uint32_t ubest = 0x7f800000u;   // +inf
    int bpack = 0;
#pragma unroll
    for (int a = 0; a < 28; ++a) {
#pragma unroll
        for (int b = a + 1; b < 28; ++b) {
            constexpr unsigned MA[28] = {3,5,9,17,33,65,129,6,10,18,34,66,130,12,20,36,68,132,24,40,72,136,48,80,144,96,160,192};
            if ((MA[a] & MA[b]) != 0u) continue;    // folds at compile time
            float num = fabsf(m[a] - m[b]);         // exact IEEE sub+abs
            float den = m[a] + m[b];                // exact IEEE add
            float v = num / den;                    // HW CR f32 divide
            uint32_t uv = fbits(v);
            bool better = uv < ubest;
            ubest = better ? uv : ubest;
            bpack = better ? (a * 32 + b) : bpack;
        }
    }

    const int ba = bpack >> 5;
    const int bb = bpack & 31;

    // Decode the two selected masses from registers via cndmask tree.
    float bma = m[0], bmb = m[0];
#pragma unroll
    for (int i = 1; i < 28; ++i) {
        bma = (ba == i) ? m[i] : bma;
        bmb = (bb == i) ? m[i] : bmb;
    }

    float* o = out + (size_t)t * 7;
    o[0] = (float)d_CI[ba];
    o[1] = (float)d_CJ[ba];
    o[2] = (float)d_CI[bb];
    o[3] = (float)d_CJ[bb];
    o[4] = bma;
    o[5] = bmb;
    o[6] = bitsf(ubest);
}

extern "C" void kernel_launch(void* const* d_in, const int* in_sizes, int n_in,
                              void* d_out, int out_size, void* d_ws, size_t ws_size,
                              hipStream_t stream) {
    const float* x = (const float*)d_in[0];
    float* out = (float*)d_out;
    const int n = in_sizes[0] / 32;          // events
    const int block = 256;
    const int grid = (n + block - 1) / block;
    mass_asym_kernel<<<grid, block, 0, stream>>>(x, out, n);
}